// Round 6
// baseline (1088.976 us; speedup 1.0000x reference)
//
#include <hip/hip_runtime.h>
#include <hip/hip_fp16.h>

#define B_ 32
#define T_ 336
#define NH 100
#define NM 150
#define FH 8
#define FM 16
#define HG 64
#define FUT 24
#define EH 300
#define EM 500

// ws layout in 4-byte elements. WRELH/WRELM/WROOT contiguous => wcat[32][64]
#define WRELH 0       // rows 0-7   : 0.5*W_rel_h^T
#define WRELM 512     // rows 8-23  : 0.5*W_rel_m^T
#define WROOT 1536    // rows 24-31 : 0.5*(W_root_h+W_root_m)^T
#define BIASC 2048    // 64
#define OFFH  2112    // 101 ints
#define SRCH  2304    // 300 ints
#define OFFM  2624    // 101 ints
#define SRCM  2752    // 500 ints
#define XBUF_F 4096   // fp16 x buffer [G][NH][HG] (float-element offset)

typedef _Float16 half8 __attribute__((ext_vector_type(8)));
typedef float floatx4 __attribute__((ext_vector_type(4)));

#define PPB 4      // graph-pairs per gnn block (grid = 5376/PPB = 1344)
#define HSTR 72    // fp16 stride of lstm h tile row (144B: b128 reads 2-way-free)

__device__ __forceinline__ float fsigmoid(float x) {
    return __builtin_amdgcn_rcpf(1.0f + __expf(-x));
}
__device__ __forceinline__ float ftanh(float x) {
    return 1.0f - 2.0f * __builtin_amdgcn_rcpf(1.0f + __expf(2.0f * x));
}
__device__ __forceinline__ float lrelu(float x) { return x >= 0.0f ? x : 0.01f * x; }

// ---------------------------------------------------------------- prep ------
__global__ __launch_bounds__(256) void prep_kernel(
    const float* __restrict__ W_rel_m, const float* __restrict__ b_rel_m,
    const float* __restrict__ W_root_m, const float* __restrict__ W_rel_h,
    const float* __restrict__ b_rel_h, const float* __restrict__ W_root_h,
    const int* __restrict__ he, const int* __restrict__ me,
    float* __restrict__ ws)
{
    const int tid = threadIdx.x;
    int* wsI = (int*)ws;
    __shared__ int cnt[NH + 1];
    __shared__ int cur[NH + 1];

    for (int idx = tid; idx < HG * FH; idx += 256) {
        int j = idx >> 3, k = idx & 7;
        ws[WRELH + k * HG + j] = 0.5f * W_rel_h[j * FH + k];
        ws[WROOT + k * HG + j] = 0.5f * (W_root_h[j * FH + k] + W_root_m[j * FH + k]);
    }
    for (int idx = tid; idx < HG * FM; idx += 256) {
        int j = idx >> 4, k = idx & 15;
        ws[WRELM + k * HG + j] = 0.5f * W_rel_m[j * FM + k];
    }
    if (tid < HG) ws[BIASC + tid] = 0.5f * (b_rel_h[tid] + b_rel_m[tid]);

    // ---- hydro CSR (tgt -> list of src) ----
    if (tid <= NH) cnt[tid] = 0;
    __syncthreads();
    for (int e = tid; e < EH; e += 256) atomicAdd(&cnt[he[EH + e]], 1);
    __syncthreads();
    if (tid == 0) {
        int s = 0;
        for (int n2 = 0; n2 < NH; ++n2) { int c = cnt[n2]; cur[n2] = s; cnt[n2] = s; s += c; }
        cnt[NH] = s;
    }
    __syncthreads();
    if (tid <= NH) wsI[OFFH + tid] = cnt[tid];
    for (int e = tid; e < EH; e += 256) {
        int t = he[EH + e];
        int p = atomicAdd(&cur[t], 1);
        wsI[SRCH + p] = he[e];
    }
    __syncthreads();

    // ---- meteo CSR ----
    if (tid <= NH) cnt[tid] = 0;
    __syncthreads();
    for (int e = tid; e < EM; e += 256) atomicAdd(&cnt[me[EM + e]], 1);
    __syncthreads();
    if (tid == 0) {
        int s = 0;
        for (int n2 = 0; n2 < NH; ++n2) { int c = cnt[n2]; cur[n2] = s; cnt[n2] = s; s += c; }
        cnt[NH] = s;
    }
    __syncthreads();
    if (tid <= NH) wsI[OFFM + tid] = cnt[tid];
    for (int e = tid; e < EM; e += 256) {
        int t = me[EM + e];
        int p = atomicAdd(&cur[t], 1);
        wsI[SRCM + p] = me[e];
    }
}

// ---------------------------------------------------------------- GNN -------
// 512 threads (8 waves = 2/SIMD). Block processes PPB graph-PAIRS.
// Per iter: async-stage next pair (global->reg early, ds_write after barrier),
// aggregate both graphs into vcat[2], then the two 256-thread halves run the
// matmul on their own graph. 2 barriers per pair.
__global__ __launch_bounds__(512) void gnn_kernel(
    const float* __restrict__ dm, const float* __restrict__ dh,
    const float* __restrict__ ws, __half* __restrict__ xout)
{
    __shared__ __align__(16) float xcomb[2 * 3200];  // [gsel][xh 800 | xm 2400] 25.6KB
    __shared__ __align__(16) float vcat[2][NH * 36]; // 28.8KB
    __shared__ __align__(16) float wcat[32 * 64];    // 8KB
    __shared__ __align__(16) float biasc[HG];
    __shared__ int offh[NH + 1], offm[NH + 1];
    __shared__ int srch[EH], srcm[EM];

    const int tid = threadIdx.x;
    const int* wsI = (const int*)ws;

    // one-time staging (512 threads: all fit in one pass)
    for (int i = tid; i < 2048 / 4; i += 512) ((float4*)wcat)[i] = ((const float4*)ws)[i];
    if (tid < HG) biasc[tid] = ws[BIASC + tid];
    if (tid <= NH) { offh[tid] = wsI[OFFH + tid]; offm[tid] = wsI[OFFM + tid]; }
    if (tid < EH) srch[tid] = wsI[SRCH + tid];
    if (tid < EM) srcm[tid] = wsI[SRCM + tid];

    const int pr0 = blockIdx.x * PPB;
    float4 stg[4];   // staged next-pair data (T14 async split)

    // pair pr -> regs (1600 float4: [gA xh|xm][gB xh|xm])
    auto load_pair = [&](int pr) {
#pragma unroll
        for (int c = 0; c < 4; ++c) {
            int f4 = tid + c * 512;
            if (f4 < 1600) {
                int gsel = f4 >= 800;
                int wi = f4 - gsel * 800;
                int g = pr * 2 + gsel;
                const float4* src = (wi < 200)
                    ? (const float4*)(dh + (size_t)g * (NH * FH)) + wi
                    : (const float4*)(dm + (size_t)g * (NM * FM)) + (wi - 200);
                stg[c] = *src;
            }
        }
    };
    auto write_pair = [&]() {
#pragma unroll
        for (int c = 0; c < 4; ++c) {
            int f4 = tid + c * 512;
            if (f4 < 1600) ((float4*)xcomb)[f4] = stg[c];
        }
    };

    // prologue: stage pair 0
    load_pair(pr0);
    write_pair();
    __syncthreads();

    const int r   = (tid & 255) >> 4;   // node residue 0..15 (within 256-group)
    const int j0  = (tid & 15) << 2;    // output column slice
    const int gmm = tid >> 8;           // matmul graph select (0/1)
    const int cnt_n = (r < 4) ? 7 : 6;  // nodes r+16i <= 99

#pragma unroll 1
    for (int it = 0; it < PPB; ++it) {
        const int pr = pr0 + it;
        if (it + 1 < PPB) load_pair(pr + 1);   // issue early; in flight during agg

        // ---- aggregation for both graphs ----
        for (int s = tid; s < 2 * NH * FH; s += 512) {
            int gsel = s >= NH * FH;
            int s2 = s - gsel * (NH * FH);
            int nn = s2 >> 3, k = s2 & 7;
            const float* xg = &xcomb[gsel * 3200];
            float a = 0.f;
            for (int e = offh[nn]; e < offh[nn + 1]; ++e) a += xg[srch[e] * FH + k];
            vcat[gsel][nn * 36 + k] = a;
            vcat[gsel][nn * 36 + 24 + k] = xg[nn * FH + k];
        }
        for (int s = tid; s < 2 * NH * FM; s += 512) {
            int gsel = s >= NH * FM;
            int s2 = s - gsel * (NH * FM);
            int nn = s2 >> 4, k = s2 & 15;
            const float* xg = &xcomb[gsel * 3200 + 800];
            float a = 0.f;
            for (int e = offm[nn]; e < offm[nn + 1]; ++e) a += xg[srcm[e] * FM + k];
            vcat[gsel][nn * 36 + 8 + k] = a;
        }
        __syncthreads();

        // xcomb reads done -> commit staged next pair (off critical path)
        if (it + 1 < PPB) write_pair();

        // ---- matmul: 256-group gmm handles graph pr*2+gmm ----
        float4 acc[7];
        const float4 bias4 = *(const float4*)&biasc[j0];
#pragma unroll
        for (int i = 0; i < 7; ++i) acc[i] = bias4;
        const float* vc = vcat[gmm];

#pragma unroll
        for (int k4 = 0; k4 < 8; ++k4) {
            float4 w0 = *(const float4*)&wcat[(4 * k4 + 0) * 64 + j0];
            float4 w1 = *(const float4*)&wcat[(4 * k4 + 1) * 64 + j0];
            float4 w2 = *(const float4*)&wcat[(4 * k4 + 2) * 64 + j0];
            float4 w3 = *(const float4*)&wcat[(4 * k4 + 3) * 64 + j0];
#pragma unroll
            for (int i = 0; i < 7; ++i) {
                if (i < cnt_n) {
                    int nn = r + 16 * i;
                    float4 va = *(const float4*)&vc[nn * 36 + 4 * k4];
                    acc[i].x += va.x * w0.x + va.y * w1.x + va.z * w2.x + va.w * w3.x;
                    acc[i].y += va.x * w0.y + va.y * w1.y + va.z * w2.y + va.w * w3.y;
                    acc[i].z += va.x * w0.z + va.y * w1.z + va.z * w2.z + va.w * w3.z;
                    acc[i].w += va.x * w0.w + va.y * w1.w + va.z * w2.w + va.w * w3.w;
                }
            }
        }

        __half* xg = xout + (size_t)(pr * 2 + gmm) * (NH * HG);
#pragma unroll
        for (int i = 0; i < 7; ++i) {
            if (i < cnt_n) {
                int nn = r + 16 * i;
                float ax = lrelu(acc[i].x), ay = lrelu(acc[i].y);
                float az = lrelu(acc[i].z), aw = lrelu(acc[i].w);
                __half2 lo = __halves2half2(__float2half_rn(ax), __float2half_rn(ay));
                __half2 hi = __halves2half2(__float2half_rn(az), __float2half_rn(aw));
                __half2* dst = (__half2*)(xg + nn * HG + j0);
                dst[0] = lo; dst[1] = hi;
            }
        }
        __syncthreads();   // vcat/xcomb safe for next iteration
    }
}

// ---------------------------------------------------------------- LSTM ------
// 200 blocks x 256 threads. Recurrence-chain-minimized:
//  - x never touches LDS: each thread loads its OWN future A-fragments
//    (2x half8, prefetched 2 steps ahead, L2-served).
//  - x-half of gates (xacc = bias + Wx*x_{t+1}) computed OFF-CHAIN at the end
//    of step t (8 MFMAs whose results are needed only next step).
//  - on-chain: barrier -> 2 ds_read h-frags -> 8 h-MFMAs -> combine -> h write.
//  - gate-column permutation (unit u = 16w+m16) keeps all 4 gates in-register.
__global__ __launch_bounds__(256) void lstm_kernel(
    const __half* __restrict__ xbuf,
    const float* __restrict__ Wih, const float* __restrict__ Whh,
    const float* __restrict__ bih, const float* __restrict__ bhh,
    const float* __restrict__ Wlin, const float* __restrict__ blin,
    float* __restrict__ out)
{
    __shared__ __align__(16) _Float16 hT[2][16 * HSTR];  // [buf][batch][unit], 2x2.25KB
    __shared__ __align__(16) float hb32[16 * 68];        // fp32 h_T for head

    const int tid = threadIdx.x;
    const int n = blockIdx.x >> 1;
    const int half_ = blockIdx.x & 1;
    const int w = tid >> 6, l = tid & 63;
    const int m16 = l & 15, g4 = l >> 4;
    const int u = 16 * w + m16;             // owned hidden unit

    // ---- B-fragments: x-part (k 0..63) and h-part (k 64..127), fp16 ----
    half8 bfx[4][2], bfh[4][2];
    float biasr[4];
#pragma unroll
    for (int g = 0; g < 4; ++g) {
        const int gcol = 64 * g + u;
        const float* wi = Wih + ((size_t)n * 256 + gcol) * 64;
        const float* wh = Whh + ((size_t)n * 256 + gcol) * 64;
        biasr[g] = bih[n * 256 + gcol] + bhh[n * 256 + gcol];
#pragma unroll
        for (int q = 0; q < 2; ++q) {
            const int kb = 32 * q + 8 * g4;
            float4 lo = *(const float4*)(wi + kb);
            float4 hi = *(const float4*)(wi + kb + 4);
            half8 f;
            f[0] = (_Float16)lo.x; f[1] = (_Float16)lo.y;
            f[2] = (_Float16)lo.z; f[3] = (_Float16)lo.w;
            f[4] = (_Float16)hi.x; f[5] = (_Float16)hi.y;
            f[6] = (_Float16)hi.z; f[7] = (_Float16)hi.w;
            bfx[g][q] = f;
            float4 lo2 = *(const float4*)(wh + kb);
            float4 hi2 = *(const float4*)(wh + kb + 4);
            half8 f2;
            f2[0] = (_Float16)lo2.x; f2[1] = (_Float16)lo2.y;
            f2[2] = (_Float16)lo2.z; f2[3] = (_Float16)lo2.w;
            f2[4] = (_Float16)hi2.x; f2[5] = (_Float16)hi2.y;
            f2[6] = (_Float16)hi2.z; f2[7] = (_Float16)hi2.w;
            bfh[g][q] = f2;
        }
    }

    // per-thread x A-fragment source: batch row m16, k-slice 8*g4 (+32 for q=1)
    const _Float16* xbase = (const _Float16*)xbuf
        + (size_t)(half_ * 16 + m16) * T_ * (NH * HG) + (size_t)n * HG + 8 * g4;

    // ---- prologue: x0/x1 frags, zero h buf0, xacc for t=0 ----
    half8 xn0, xn1;   // frags of x_{t+1}
    floatx4 xacc[4];
    {
        const _Float16* p0 = xbase;                       // t = 0
        half8 xc0 = *(const half8*)p0;
        half8 xc1 = *(const half8*)(p0 + 32);
        const _Float16* p1 = xbase + (size_t)(T_ > 1 ? 1 : 0) * (NH * HG);
        xn0 = *(const half8*)p1;
        xn1 = *(const half8*)(p1 + 32);
#pragma unroll
        for (int g = 0; g < 4; ++g) {
            floatx4 a = {biasr[g], biasr[g], biasr[g], biasr[g]};
            a = __builtin_amdgcn_mfma_f32_16x16x32_f16(xc0, bfx[g][0], a, 0, 0, 0);
            a = __builtin_amdgcn_mfma_f32_16x16x32_f16(xc1, bfx[g][1], a, 0, 0, 0);
            xacc[g] = a;
        }
    }
    for (int i = tid; i < 16 * HSTR; i += 256) hT[0][i] = (_Float16)0.f;
    __syncthreads();

    float cc[4] = {0.f, 0.f, 0.f, 0.f};
    int p = 0;

#pragma unroll 1
    for (int t = 0; t < T_; ++t) {
        // issue x_{t+2} prefetch (consumed next step, off-chain)
        const int tf = (t + 2 < T_) ? (t + 2) : (T_ - 1);
        const _Float16* pf = xbase + (size_t)tf * (NH * HG);
        half8 xf0 = *(const half8*)pf;
        half8 xf1 = *(const half8*)(pf + 32);

        // ---- on-chain: h-frags -> 8 MFMAs ----
        half8 hf0 = *(const half8*)&hT[p][m16 * HSTR + 8 * g4];
        half8 hf1 = *(const half8*)&hT[p][m16 * HSTR + 32 + 8 * g4];

        floatx4 acc[4];
#pragma unroll
        for (int g = 0; g < 4; ++g) {
            floatx4 a = __builtin_amdgcn_mfma_f32_16x16x32_f16(hf0, bfh[g][0], xacc[g], 0, 0, 0);
            acc[g] = __builtin_amdgcn_mfma_f32_16x16x32_f16(hf1, bfh[g][1], a, 0, 0, 0);
        }

        // ---- combine (in-register), write h_t ----
        _Float16* nb = &hT[p ^ 1][0];
#pragma unroll
        for (int rr = 0; rr < 4; ++rr) {
            const int bb = 4 * g4 + rr;
            float ai = acc[0][rr], af = acc[1][rr], ag = acc[2][rr], ao = acc[3][rr];
            float c = fsigmoid(af) * cc[rr] + fsigmoid(ai) * ftanh(ag);
            cc[rr] = c;
            float h = fsigmoid(ao) * ftanh(c);
            nb[bb * HSTR + u] = (_Float16)h;
            if (t == T_ - 1) hb32[bb * 68 + u] = h;
        }

        // ---- off-chain: xacc for step t+1 (uses x_{t+1}) ----
#pragma unroll
        for (int g = 0; g < 4; ++g) {
            floatx4 a = {biasr[g], biasr[g], biasr[g], biasr[g]};
            a = __builtin_amdgcn_mfma_f32_16x16x32_f16(xn0, bfx[g][0], a, 0, 0, 0);
            xacc[g] = __builtin_amdgcn_mfma_f32_16x16x32_f16(xn1, bfx[g][1], a, 0, 0, 0);
        }
        xn0 = xf0; xn1 = xf1;

        __syncthreads();   // h_t visible; single barrier per step
        p ^= 1;
    }

    // ---- head: pred = leaky(h_T @ W_lin^T + b_lin) ----
    for (int task = tid; task < 16 * FUT; task += 256) {
        int b = task / FUT, j = task - b * FUT;
        float accv = blin[j];
        const float* wl = Wlin + j * 64;
        const float* hr = &hb32[b * 68];
#pragma unroll
        for (int k = 0; k < 64; k += 4) {
            float4 wv = *(const float4*)&wl[k];
            accv += wv.x * hr[k] + wv.y * hr[k + 1] + wv.z * hr[k + 2] + wv.w * hr[k + 3];
        }
        out[((size_t)(half_ * 16 + b) * NH + n) * FUT + j] = lrelu(accv);
    }
}

// ---------------------------------------------------------------- launch ----
extern "C" void kernel_launch(void* const* d_in, const int* in_sizes, int n_in,
                              void* d_out, int out_size, void* d_ws, size_t ws_size,
                              hipStream_t stream)
{
    const float* dm       = (const float*)d_in[0];
    const float* dh       = (const float*)d_in[1];
    const int*   he       = (const int*)d_in[2];
    const int*   me       = (const int*)d_in[3];
    const float* W_rel_m  = (const float*)d_in[4];
    const float* b_rel_m  = (const float*)d_in[5];
    const float* W_root_m = (const float*)d_in[6];
    const float* W_rel_h  = (const float*)d_in[7];
    const float* b_rel_h  = (const float*)d_in[8];
    const float* W_root_h = (const float*)d_in[9];
    const float* Wih      = (const float*)d_in[10];
    const float* Whh      = (const float*)d_in[11];
    const float* bih      = (const float*)d_in[12];
    const float* bhh      = (const float*)d_in[13];
    const float* Wlin     = (const float*)d_in[14];
    const float* blin     = (const float*)d_in[15];

    float* ws = (float*)d_ws;
    __half* xbuf = (__half*)(ws + XBUF_F);
    float* out = (float*)d_out;

    prep_kernel<<<1, 256, 0, stream>>>(W_rel_m, b_rel_m, W_root_m,
                                       W_rel_h, b_rel_h, W_root_h, he, me, ws);
    gnn_kernel<<<(B_ * T_) / (2 * PPB), 512, 0, stream>>>(dm, dh, ws, xbuf);
    lstm_kernel<<<NH * 2, 256, 0, stream>>>(xbuf, Wih, Whh, bih, bhh, Wlin, blin, out);
}